// Round 1
// baseline (318.992 us; speedup 1.0000x reference)
//
#include <hip/hip_runtime.h>

// Problem constants
#define QN    2048          // queries
#define SS    8             // frames per video
#define DD    2048          // feature dim
#define SP    100           // support videos
#define NCLS  20
#define MROWS (QN*SS)       // 16384 GEMM M
#define NROWS (SP*SS)       // 800   GEMM N (logical)
#define NPAD  896           // N padded to 7*128
#define KK    DD            // 2048  GEMM K

typedef __bf16 bf16x8 __attribute__((ext_vector_type(8)));
typedef float  f32x4  __attribute__((ext_vector_type(4)));

__device__ __forceinline__ unsigned short f2bf(float f) {
    unsigned int u = __float_as_uint(f);
    u += 0x7fffu + ((u >> 16) & 1u);   // round-to-nearest-even
    return (unsigned short)(u >> 16);
}

// ---------------- Kernel 1: fp32 -> bf16 conversion + row L2 norms ----------------
// grid = MROWS + NPAD blocks, 256 threads; one row (2048 elems) per block.
__global__ void cvt_kernel(const float* __restrict__ tf, const float* __restrict__ sf,
                           unsigned short* __restrict__ Abf, unsigned short* __restrict__ Bbf,
                           float* __restrict__ nA, float* __restrict__ nB)
{
    int row = blockIdx.x;
    int tid = threadIdx.x;
    const float* src = nullptr;
    unsigned short* dst;
    float* nrm; int r;
    if (row < MROWS) { src = tf + (size_t)row * DD; dst = Abf + (size_t)row * DD; nrm = nA; r = row; }
    else {
        r = row - MROWS;
        dst = Bbf + (size_t)r * DD; nrm = nB;
        if (r < NROWS) src = sf + (size_t)r * DD;   // rows [800,896) stay zero
    }
    float s = 0.f;
    union { uint4 u; unsigned short h[8]; } pk;
    if (src) {
        float4 v0 = *(const float4*)(src + tid * 8);
        float4 v1 = *(const float4*)(src + tid * 8 + 4);
        s = v0.x*v0.x + v0.y*v0.y + v0.z*v0.z + v0.w*v0.w
          + v1.x*v1.x + v1.y*v1.y + v1.z*v1.z + v1.w*v1.w;
        pk.h[0]=f2bf(v0.x); pk.h[1]=f2bf(v0.y); pk.h[2]=f2bf(v0.z); pk.h[3]=f2bf(v0.w);
        pk.h[4]=f2bf(v1.x); pk.h[5]=f2bf(v1.y); pk.h[6]=f2bf(v1.z); pk.h[7]=f2bf(v1.w);
    } else {
        pk.u = make_uint4(0, 0, 0, 0);
    }
    *(uint4*)(dst + (size_t)tid * 8) = pk.u;

    for (int o = 32; o; o >>= 1) s += __shfl_down(s, o);
    __shared__ float red[4];
    if ((tid & 63) == 0) red[tid >> 6] = s;
    __syncthreads();
    if (tid == 0) nrm[r] = sqrtf(red[0] + red[1] + red[2] + red[3]);
}

// ---------------- Kernel 2: bf16 MFMA GEMM, C = A*B^T, epilogue 1 - dot/(nx*ny+eps) --------
__device__ __forceinline__ void gld16(const void* g, void* l) {
    __builtin_amdgcn_global_load_lds(
        (const __attribute__((address_space(1))) unsigned int*)g,
        (__attribute__((address_space(3))) unsigned int*)l, 16, 0, 0);
}

__global__ __launch_bounds__(256, 2) void gemm_kernel(
    const unsigned short* __restrict__ A,   // [MROWS][K] bf16 bits
    const unsigned short* __restrict__ B,   // [NPAD][K]  bf16 bits
    const float* __restrict__ nA, const float* __restrict__ nB,
    float* __restrict__ Dout)               // [MROWS][NROWS] fp32 distances
{
    __shared__ __align__(16) unsigned short Als[128 * 32];
    __shared__ __align__(16) unsigned short Bls[128 * 32];
    const int mt  = blockIdx.x;      // 0..127
    const int nt  = blockIdx.y;      // 0..6
    const int tid = threadIdx.x;
    const int lane = tid & 63;
    const int w    = tid >> 6;
    const int wm   = (w & 1) * 64, wn = (w >> 1) * 64;
    const int col  = lane & 15, kg = lane >> 4;

    f32x4 acc[4][4] = {};

    // staging: 512 16B-chunks per tile, 2 per thread. chunk c -> row c>>2, k-sub (c&3)*8
    const int c0 = tid, c1 = tid + 256;
    const unsigned short* Ab0 = A + (size_t)mt * 128 * KK + (size_t)(c0 >> 2) * KK + (c0 & 3) * 8;
    const unsigned short* Ab1 = A + (size_t)mt * 128 * KK + (size_t)(c1 >> 2) * KK + (c1 & 3) * 8;
    const unsigned short* Bb0 = B + (size_t)nt * 128 * KK + (size_t)(c0 >> 2) * KK + (c0 & 3) * 8;
    const unsigned short* Bb1 = B + (size_t)nt * 128 * KK + (size_t)(c1 >> 2) * KK + (c1 & 3) * 8;

    for (int kk = 0; kk < KK; kk += 32) {
        __syncthreads();
        gld16(Ab0 + kk, (char*)Als + c0 * 16);
        gld16(Ab1 + kk, (char*)Als + c1 * 16);
        gld16(Bb0 + kk, (char*)Bls + c0 * 16);
        gld16(Bb1 + kk, (char*)Bls + c1 * 16);
        __syncthreads();
        bf16x8 af[4], bfr[4];
#pragma unroll
        for (int i = 0; i < 4; i++) af[i]  = *(const bf16x8*)(Als + (wm + i * 16 + col) * 32 + kg * 8);
#pragma unroll
        for (int i = 0; i < 4; i++) bfr[i] = *(const bf16x8*)(Bls + (wn + i * 16 + col) * 32 + kg * 8);
#pragma unroll
        for (int mi = 0; mi < 4; mi++)
#pragma unroll
            for (int ni = 0; ni < 4; ni++)
                acc[mi][ni] = __builtin_amdgcn_mfma_f32_16x16x32_bf16(af[mi], bfr[ni], acc[mi][ni], 0, 0, 0);
    }

    const int mbase = mt * 128 + wm;
    const int nbase = nt * 128 + wn;
#pragma unroll
    for (int ni = 0; ni < 4; ni++) {
        int n = nbase + ni * 16 + col;
        if (n < NROWS) {
            float ny = nB[n];
#pragma unroll
            for (int mi = 0; mi < 4; mi++) {
#pragma unroll
                for (int r = 0; r < 4; r++) {
                    int m = mbase + mi * 16 + kg * 4 + r;
                    float nx = nA[m];
                    Dout[(size_t)m * NROWS + n] = 1.0f - acc[mi][ni][r] / (nx * ny + 0.01f);
                }
            }
        }
    }
}

// ---------------- Kernel 3: OTAM DP (both directions) per (q,sp) pair ----------------
__device__ __forceinline__ float softmin2(float a, float b) {
    float mn = fminf(a, b), mx = fmaxf(a, b);
    return mn - 0.1f * __logf(1.0f + __expf((mn - mx) * 10.0f));
}
__device__ __forceinline__ float softmin3(float a, float b, float c) {
    float mn = fminf(fminf(a, b), c);
    float sum = __expf((mn - a) * 10.0f) + __expf((mn - b) * 10.0f) + __expf((mn - c) * 10.0f);
    return mn - 0.1f * __logf(sum);
}

__global__ void dp_kernel(const float* __restrict__ dist, float* __restrict__ cum)
{
    int idx = blockIdx.x * 256 + threadIdx.x;    // 204800 exactly
    int q = idx / SP, sp = idx % SP;
    float t[8][8];
    const float* base = dist + (size_t)q * 8 * NROWS + sp * 8;
#pragma unroll
    for (int i = 0; i < 8; i++) {
        float4 a = *(const float4*)(base + (size_t)i * NROWS);
        float4 b = *(const float4*)(base + (size_t)i * NROWS + 4);
        t[i][0]=a.x; t[i][1]=a.y; t[i][2]=a.z; t[i][3]=a.w;
        t[i][4]=b.x; t[i][5]=b.y; t[i][6]=b.z; t[i][7]=b.w;
    }
    float res = 0.f;
#pragma unroll
    for (int dir = 0; dir < 2; dir++) {
        float prev[10], cur[10];
        prev[0] = 0.f;
#pragma unroll
        for (int m = 1; m <= 8; m++) prev[m] = prev[m - 1] + (dir ? t[m - 1][0] : t[0][m - 1]);
        prev[9] = prev[8];
#pragma unroll
        for (int l = 1; l < 8; l++) {
            cur[0] = 0.f;
            cur[1] = (dir ? t[0][l] : t[l][0]) + softmin3(prev[0], prev[1], 0.0f);
#pragma unroll
            for (int m = 2; m <= 8; m++)
                cur[m] = (dir ? t[m - 1][l] : t[l][m - 1]) + softmin2(prev[m - 1], cur[m - 1]);
            cur[9] = softmin3(prev[8], prev[9], cur[8]);   // pad column: d=0
#pragma unroll
            for (int m = 0; m < 10; m++) prev[m] = cur[m];
        }
        res += prev[9];
    }
    cum[idx] = res;
}

// ---------------- Kernel 4: per-class mean -> logits ----------------
__global__ void cls_kernel(const float* __restrict__ cum, const int* __restrict__ labels,
                           float* __restrict__ out)
{
    int idx = blockIdx.x * 256 + threadIdx.x;   // 40960 exactly
    int q = idx / NCLS, c = idx % NCLS;
    float s = 0.f; int n = 0;
    const float* row = cum + (size_t)q * SP;
    for (int sp = 0; sp < SP; sp++) {
        if (labels[sp] == c) { s += row[sp]; n++; }
    }
    out[idx] = -s / (float)n;
}

// ---------------- launch ----------------
extern "C" void kernel_launch(void* const* d_in, const int* in_sizes, int n_in,
                              void* d_out, int out_size, void* d_ws, size_t ws_size,
                              hipStream_t stream)
{
    const float* tf     = (const float*)d_in[0];   // [2048,8,2048] f32
    const float* sf     = (const float*)d_in[1];   // [100,8,2048]  f32
    const int*   labels = (const int*)d_in[2];     // [100] i32
    float* out = (float*)d_out;                    // [1,2048,20] f32

    char* ws = (char*)d_ws;
    const size_t szA    = (size_t)MROWS * KK * 2;      // 67108864
    const size_t szB    = (size_t)NPAD  * KK * 2;      // 3670016
    const size_t szNA   = (size_t)MROWS * 4;           // 65536
    const size_t szNB   = (size_t)NPAD  * 4;           // 3584
    const size_t szDist = (size_t)MROWS * NROWS * 4;   // 52428800
    unsigned short* Abf = (unsigned short*)ws;
    unsigned short* Bbf = (unsigned short*)(ws + szA);
    float* nA   = (float*)(ws + szA + szB);
    float* nB   = (float*)(ws + szA + szB + szNA);
    float* dist = (float*)(ws + szA + szB + szNA + szNB);
    float* cum  = (float*)(ws + szA + szB + szNA + szNB + szDist);

    cvt_kernel<<<MROWS + NPAD, 256, 0, stream>>>(tf, sf, Abf, Bbf, nA, nB);
    gemm_kernel<<<dim3(128, 7), 256, 0, stream>>>(Abf, Bbf, nA, nB, dist);
    dp_kernel<<<800, 256, 0, stream>>>(dist, cum);
    cls_kernel<<<160, 256, 0, stream>>>(cum, labels, out);
}